// Round 1
// baseline (401.357 us; speedup 1.0000x reference)
//
#include <hip/hip_runtime.h>
#include <math.h>

// Problem constants (fixed by setup_inputs)
#define TT 16384   // tokens
#define HH 2048    // hidden dim
#define EE 64      // experts
#define KK 8       // top_k

// Tiling
#define TB 32            // tokens per block
#define HC 64            // h-chunk
#define NCHUNK (HH / HC) // 32

#define LH_STRIDE (TB + 1)        // 33 (pad for LDS bank spread)
#define LW_STRIDE (EE + 1)        // 65
#define LH_SIZE (HC * LH_STRIDE)  // 2112 doubles
#define LW_SIZE (HC * LW_STRIDE)  // 4160 doubles
#define EP_STRIDE 65              // epilogue row stride

// Output layout (all written as float32 in one flat buffer):
// probs   [TT][KK]  at 0
// indices [TT][KK]  at TT*KK        (written as float(idx))
// map     [TT][EE]  at 2*TT*KK      (1.0f / 0.0f)
// aux     scalar    at 2*TT*KK + TT*EE
#define IDX_OFF ((size_t)TT * KK)
#define MAP_OFF ((size_t)2 * TT * KK)
#define AUX_OFF ((size_t)2 * TT * KK + (size_t)TT * EE)

__global__ __launch_bounds__(256, 2)
void router_kernel(const float* __restrict__ hidden,
                   const float* __restrict__ gate_w,
                   const float* __restrict__ bias,
                   float* __restrict__ out)
{
    // Staging buffers (fp64, transposed to [h][t] / [h][e]); epilogue overlays.
    __shared__ double smem[LH_SIZE + LW_SIZE];          // 50,176 B
    __shared__ unsigned long long msk[TB];

    double* ldsH = smem;            // [HC][LH_STRIDE]
    double* ldsW = smem + LH_SIZE;  // [HC][LW_STRIDE]

    const int tid = threadIdx.x;
    const int ti = tid >> 4;   // 0..15 -> tokens 2ti, 2ti+1
    const int tj = tid & 15;   // 0..15 -> experts 4tj..4tj+3
    const int tok0 = blockIdx.x * TB;

    double acc[2][4];
    #pragma unroll
    for (int i = 0; i < 2; ++i)
        #pragma unroll
        for (int j = 0; j < 4; ++j) acc[i][j] = 0.0;

    for (int c = 0; c < NCHUNK; ++c) {
        const int h0 = c * HC;

        // ---- stage hidden tile: 32 tok x 64 h -> ldsH[h][t] (fp64) ----
        #pragma unroll
        for (int r = 0; r < 2; ++r) {
            int s  = r * 256 + tid;        // 0..511 float4 slots
            int t  = s >> 4;               // 16 float4 per token row
            int h4 = (s & 15) << 2;
            float4 v = *reinterpret_cast<const float4*>(
                hidden + (size_t)(tok0 + t) * HH + h0 + h4);
            ldsH[(h4 + 0) * LH_STRIDE + t] = (double)v.x;
            ldsH[(h4 + 1) * LH_STRIDE + t] = (double)v.y;
            ldsH[(h4 + 2) * LH_STRIDE + t] = (double)v.z;
            ldsH[(h4 + 3) * LH_STRIDE + t] = (double)v.w;
        }
        // ---- stage gate_w tile: 64 e x 64 h -> ldsW[h][e] (fp64) ----
        #pragma unroll
        for (int r = 0; r < 4; ++r) {
            int s  = r * 256 + tid;        // 0..1023
            int e  = s >> 4;
            int h4 = (s & 15) << 2;
            float4 v = *reinterpret_cast<const float4*>(
                gate_w + (size_t)e * HH + h0 + h4);
            ldsW[(h4 + 0) * LW_STRIDE + e] = (double)v.x;
            ldsW[(h4 + 1) * LW_STRIDE + e] = (double)v.y;
            ldsW[(h4 + 2) * LW_STRIDE + e] = (double)v.z;
            ldsW[(h4 + 3) * LW_STRIDE + e] = (double)v.w;
        }
        __syncthreads();

        // ---- compute: 2 tokens x 4 experts per thread, fp64 FMA ----
        #pragma unroll 8
        for (int h = 0; h < HC; ++h) {
            double hv0 = ldsH[h * LH_STRIDE + 2 * ti + 0];
            double hv1 = ldsH[h * LH_STRIDE + 2 * ti + 1];
            double w0 = ldsW[h * LW_STRIDE + 4 * tj + 0];
            double w1 = ldsW[h * LW_STRIDE + 4 * tj + 1];
            double w2 = ldsW[h * LW_STRIDE + 4 * tj + 2];
            double w3 = ldsW[h * LW_STRIDE + 4 * tj + 3];
            acc[0][0] += hv0 * w0; acc[0][1] += hv0 * w1;
            acc[0][2] += hv0 * w2; acc[0][3] += hv0 * w3;
            acc[1][0] += hv1 * w0; acc[1][1] += hv1 * w1;
            acc[1][2] += hv1 * w2; acc[1][3] += hv1 * w3;
        }
        __syncthreads();
    }

    // ---- epilogue: overlay shared memory ----
    double* lg  = smem;                              // [TB][EP_STRIDE] logits
    double* sc  = smem + LH_SIZE;                    // [TB][EP_STRIDE] exp(l-m)
    double* sel = smem + LH_SIZE + TB * EP_STRIDE;   // [TB][EP_STRIDE] selection

    #pragma unroll
    for (int i = 0; i < 2; ++i)
        #pragma unroll
        for (int j = 0; j < 4; ++j)
            lg[(2 * ti + i) * EP_STRIDE + (4 * tj + j)] = acc[i][j];
    __syncthreads();

    if (tid < TB) {
        const int t = tid;
        const double* L = lg + (size_t)t * EP_STRIDE;

        double m = -INFINITY;
        for (int e = 0; e < EE; ++e) m = fmax(m, L[e]);

        double sum = 0.0;
        for (int e = 0; e < EE; ++e) {
            double ex = exp(L[e] - m);
            sc[t * EP_STRIDE + e] = ex;
            sum += ex;
        }
        double inv = 1.0 / sum;

        // selection scores = softmax + bias (fp64, exact ranking)
        for (int e = 0; e < EE; ++e)
            sel[t * EP_STRIDE + e] = sc[t * EP_STRIDE + e] * inv + (double)bias[e];

        unsigned long long mk = 0ull;
        double p[KK];
        int pidx[KK];
        #pragma unroll
        for (int k = 0; k < KK; ++k) {
            double best = -INFINITY;
            int bi = 0;
            for (int e = 0; e < EE; ++e) {
                double v = sel[t * EP_STRIDE + e];
                if (v > best) { best = v; bi = e; }  // strict > : ties -> lowest idx
            }
            sel[t * EP_STRIDE + bi] = -INFINITY;
            pidx[k] = bi;
            p[k] = sc[t * EP_STRIDE + bi] * inv;     // original softmax score
            mk |= (1ull << bi);
        }
        msk[t] = mk;

        double ps = 0.0;
        #pragma unroll
        for (int k = 0; k < KK; ++k) ps += p[k];
        double rinv = 1.0 / (ps + 1e-9);

        float* po = out + (size_t)(tok0 + t) * KK;
        float* io = out + IDX_OFF + (size_t)(tok0 + t) * KK;
        #pragma unroll
        for (int k = 0; k < KK; ++k) {
            po[k] = (float)(p[k] * rinv);
            io[k] = (float)pidx[k];
        }
    }
    __syncthreads();

    // ---- routing map: 32x64 floats per block, 8 per thread (coalesced) ----
    {
        int t  = tid >> 3;
        int e0 = (tid & 7) << 3;
        unsigned long long mk = msk[t];
        float* mo = out + MAP_OFF + (size_t)(tok0 + t) * EE + e0;
        #pragma unroll
        for (int k = 0; k < 8; ++k)
            mo[k] = ((mk >> (e0 + k)) & 1ull) ? 1.0f : 0.0f;
    }

    if (blockIdx.x == 0 && tid == 0)
        out[AUX_OFF] = 0.0f;
}

extern "C" void kernel_launch(void* const* d_in, const int* in_sizes, int n_in,
                              void* d_out, int out_size, void* d_ws, size_t ws_size,
                              hipStream_t stream) {
    const float* hidden = (const float*)d_in[0];  // [16384, 2048] f32
    const float* gate_w = (const float*)d_in[1];  // [64, 2048] f32
    const float* bias   = (const float*)d_in[2];  // [64] f32
    float* out = (float*)d_out;

    router_kernel<<<TT / TB, 256, 0, stream>>>(hidden, gate_w, bias, out);
}

// Round 2
// 142.725 us; speedup vs baseline: 2.8121x; 2.8121x over previous
//
#include <hip/hip_runtime.h>
#include <math.h>

// Problem constants
#define TT 16384   // tokens
#define HH 2048    // hidden
#define EE 64      // experts
#define KK 8       // top_k

// Tiling
#define TB 32            // tokens per block
#define HC 64            // h per chunk
#define NCH (HH / HC)    // 32 chunks
#define NHP (HC / 2)     // 32 h-pairs per chunk

// LDS (doubles), h-pair interleaved + XOR swizzled:
//  ldsH[(h>>1)*64  + 2*(t ^ ((h>>1)&6)) + (h&1)]   t in [0,32)
//  ldsW[(h>>1)*128 + 2*(e ^ ((h>>1)&7)) + (h&1)]   e in [0,64)
#define LDSH_SZ (NHP * 64)    // 2048 doubles (16 KB)
#define LDSW_SZ (NHP * 128)   // 4096 doubles (32 KB)

// Output layout (flat float32):
// probs [TT][KK] | indices [TT][KK] | map [TT][EE] | aux scalar
#define IDX_OFF ((size_t)TT * KK)
#define MAP_OFF ((size_t)2 * TT * KK)
#define AUX_OFF ((size_t)2 * TT * KK + (size_t)TT * EE)

__global__ __launch_bounds__(256, 3)
void router_kernel(const float* __restrict__ hidden,
                   const float* __restrict__ gate_w,
                   const float* __restrict__ bias,
                   float* __restrict__ out)
{
    __shared__ double smem[LDSH_SZ + LDSW_SZ];   // 48 KB; epilogue overlays
    double* ldsH = smem;
    double* ldsW = smem + LDSH_SZ;

    const int tid = threadIdx.x;
    const int tg  = tid >> 4;    // 0..15 : tokens 2tg, 2tg+1
    const int eg  = tid & 15;    // experts eg + 16m, m=0..3
    const int tok0 = blockIdx.x * TB;

    // acc[i][m] = logit(token 2tg+i, expert eg+16m), fp64
    double acc[2][4];
    #pragma unroll
    for (int i = 0; i < 2; ++i)
        #pragma unroll
        for (int m = 0; m < 4; ++m) acc[i][m] = 0.0;

    for (int c = 0; c < NCH; ++c) {
        const int h0 = c * HC;

        // ---- global loads (overlap previous chunk's compute) ----
        float4 hv[2], wv[4];
        #pragma unroll
        for (int k = 0; k < 2; ++k) {
            int slot = tid + 256 * k;
            int t = slot >> 4, f4 = slot & 15;
            hv[k] = *reinterpret_cast<const float4*>(
                hidden + (size_t)(tok0 + t) * HH + h0 + 4 * f4);
        }
        #pragma unroll
        for (int k = 0; k < 4; ++k) {
            int slot = tid + 256 * k;
            int e = slot >> 4, f4 = slot & 15;
            wv[k] = *reinterpret_cast<const float4*>(
                gate_w + (size_t)e * HH + h0 + 4 * f4);
        }
        __syncthreads();   // previous compute finished before overwrite

        // ---- stage H (fp64, swizzled), 2x2 ds_write_b128 ----
        #pragma unroll
        for (int k = 0; k < 2; ++k) {
            int slot = tid + 256 * k;
            int t = slot >> 4, f4 = slot & 15;
            int r0 = 2 * f4;            // even
            int X  = r0 & 6;            // same for r0 and r0+1
            *reinterpret_cast<double2*>(&ldsH[(size_t)r0 * 64 + 2 * (t ^ X)]) =
                make_double2((double)hv[k].x, (double)hv[k].y);
            *reinterpret_cast<double2*>(&ldsH[(size_t)(r0 + 1) * 64 + 2 * (t ^ X)]) =
                make_double2((double)hv[k].z, (double)hv[k].w);
        }
        // ---- stage W (fp64, swizzled), 4x2 ds_write_b128 ----
        #pragma unroll
        for (int k = 0; k < 4; ++k) {
            int slot = tid + 256 * k;
            int e = slot >> 4, f4 = slot & 15;
            int r0 = 2 * f4;            // even
            int X0 = r0 & 7;            // even; r0+1 -> X0|1
            *reinterpret_cast<double2*>(&ldsW[(size_t)r0 * 128 + 2 * (e ^ X0)]) =
                make_double2((double)wv[k].x, (double)wv[k].y);
            *reinterpret_cast<double2*>(&ldsW[(size_t)(r0 + 1) * 128 + 2 * (e ^ (X0 | 1))]) =
                make_double2((double)wv[k].z, (double)wv[k].w);
        }
        __syncthreads();

        // ---- compute: fully unrolled, const LDS offsets, 16 fp64 FMA / h-pair ----
        #pragma unroll
        for (int u = 0; u < 4; ++u) {
            #pragma unroll
            for (int w = 0; w < 8; ++w) {
                const int hh = 8 * u + w;
                const int hbase = hh * 64 + 2 * ((2 * tg) ^ (w & 6));
                const double2 ha = *reinterpret_cast<const double2*>(&ldsH[hbase]);      // token 2tg
                const double2 hb = *reinterpret_cast<const double2*>(&ldsH[hbase + 2]);  // token 2tg+1
                #pragma unroll
                for (int m = 0; m < 4; ++m) {
                    const double2 wd = *reinterpret_cast<const double2*>(
                        &ldsW[hh * 128 + 2 * (eg ^ w) + 32 * m]);
                    acc[0][m] = fma(ha.x, wd.x, acc[0][m]);
                    acc[0][m] = fma(ha.y, wd.y, acc[0][m]);
                    acc[1][m] = fma(hb.x, wd.x, acc[1][m]);
                    acc[1][m] = fma(hb.y, wd.y, acc[1][m]);
                }
            }
        }
    }
    __syncthreads();   // compute done before epilogue overlays smem

    // ---- epilogue: logits -> lg[t][e] (stride 65), then 8 lanes per token ----
    double* lg = smem;   // 32*65 = 2080 doubles
    #pragma unroll
    for (int i = 0; i < 2; ++i)
        #pragma unroll
        for (int m = 0; m < 4; ++m)
            lg[(size_t)(2 * tg + i) * 65 + eg + 16 * m] = acc[i][m];
    __syncthreads();

    const int t = tid >> 3;   // 0..31
    const int q = tid & 7;    // 0..7 lanes per token; lane owns experts q+8i
    const int tok = tok0 + t;

    double lv[8];
    #pragma unroll
    for (int i = 0; i < 8; ++i) lv[i] = lg[(size_t)t * 65 + q + 8 * i];

    // row max (fmax is exact -> order-independent)
    double mx = lv[0];
    #pragma unroll
    for (int i = 1; i < 8; ++i) mx = fmax(mx, lv[i]);
    #pragma unroll
    for (int s = 1; s < 8; s <<= 1) mx = fmax(mx, __shfl_xor(mx, s, 64));

    // exp + denom
    double ex[8];
    double psum = 0.0;
    #pragma unroll
    for (int i = 0; i < 8; ++i) { ex[i] = exp(lv[i] - mx); psum += ex[i]; }
    #pragma unroll
    for (int s = 1; s < 8; s <<= 1) psum += __shfl_xor(psum, s, 64);
    const double inv = 1.0 / psum;

    // probs + selection scores (registers only)
    double pr[8], selv[8];
    #pragma unroll
    for (int i = 0; i < 8; ++i) {
        pr[i]   = ex[i] * inv;
        selv[i] = pr[i] + (double)bias[q + 8 * i];
    }

    // top-8: per pass, lane-local argmax over 8 regs, then 3-step shfl reduce
    unsigned long long mk = 0ull;
    double myprob = 0.0;
    int myidx = 0;
    #pragma unroll
    for (int k = 0; k < KK; ++k) {
        double bs = selv[0], bp = pr[0];
        int bi = q;
        #pragma unroll
        for (int i = 1; i < 8; ++i) {
            if (selv[i] > bs) { bs = selv[i]; bp = pr[i]; bi = q + 8 * i; }
        }
        #pragma unroll
        for (int s = 1; s < 8; s <<= 1) {
            double os = __shfl_xor(bs, s, 64);
            double op = __shfl_xor(bp, s, 64);
            int    oi = __shfl_xor(bi, s, 64);
            if (os > bs || (os == bs && oi < bi)) { bs = os; bp = op; bi = oi; }
        }
        // all 8 lanes agree on winner (bs, bp, bi)
        if (q == k) { myprob = bp; myidx = bi; }
        mk |= (1ull << bi);
        #pragma unroll
        for (int i = 0; i < 8; ++i)
            if (q + 8 * i == bi) selv[i] = -INFINITY;
    }

    // renormalize over the 8 winners
    double ps = myprob;
    #pragma unroll
    for (int s = 1; s < 8; s <<= 1) ps += __shfl_xor(ps, s, 64);
    const double rinv = 1.0 / (ps + 1e-9);

    out[(size_t)tok * KK + q]           = (float)(myprob * rinv);
    out[IDX_OFF + (size_t)tok * KK + q] = (float)myidx;

    // routing map: lane q writes experts 8q..8q+7 as two float4
    {
        float4 a, b;
        a.x = ((mk >> (8 * q + 0)) & 1ull) ? 1.0f : 0.0f;
        a.y = ((mk >> (8 * q + 1)) & 1ull) ? 1.0f : 0.0f;
        a.z = ((mk >> (8 * q + 2)) & 1ull) ? 1.0f : 0.0f;
        a.w = ((mk >> (8 * q + 3)) & 1ull) ? 1.0f : 0.0f;
        b.x = ((mk >> (8 * q + 4)) & 1ull) ? 1.0f : 0.0f;
        b.y = ((mk >> (8 * q + 5)) & 1ull) ? 1.0f : 0.0f;
        b.z = ((mk >> (8 * q + 6)) & 1ull) ? 1.0f : 0.0f;
        b.w = ((mk >> (8 * q + 7)) & 1ull) ? 1.0f : 0.0f;
        float* mo = out + MAP_OFF + (size_t)tok * EE + 8 * q;
        reinterpret_cast<float4*>(mo)[0] = a;
        reinterpret_cast<float4*>(mo)[1] = b;
    }

    if (blockIdx.x == 0 && tid == 0) out[AUX_OFF] = 0.0f;
}

extern "C" void kernel_launch(void* const* d_in, const int* in_sizes, int n_in,
                              void* d_out, int out_size, void* d_ws, size_t ws_size,
                              hipStream_t stream) {
    const float* hidden = (const float*)d_in[0];  // [16384, 2048] f32
    const float* gate_w = (const float*)d_in[1];  // [64, 2048] f32
    const float* bias   = (const float*)d_in[2];  // [64] f32
    float* out = (float*)d_out;

    router_kernel<<<TT / TB, 256, 0, stream>>>(hidden, gate_w, bias, out);
}

// Round 3
// 124.019 us; speedup vs baseline: 3.2363x; 1.1508x over previous
//
#include <hip/hip_runtime.h>
#include <math.h>

// Problem constants
#define TT 16384   // tokens
#define HH 2048    // hidden
#define EE 64      // experts
#define KK 8       // top_k

#define TB 32          // tokens per block
#define HC 64          // h per chunk
#define NCH (HH / HC)  // 32 chunks

// Output layout (flat float32):
// probs [TT][KK] | indices [TT][KK] | map [TT][EE] | aux scalar
#define IDX_OFF ((size_t)TT * KK)
#define MAP_OFF ((size_t)2 * TT * KK)
#define AUX_OFF ((size_t)2 * TT * KK + (size_t)TT * EE)

// LDS staging (fp32 float4, padded strides for 2-way-max bank access):
//  stH[f4][t] : f4 0..15, stride 33, t 0..31   (8448 B)
//  stW[f4][e] : f4 0..15, stride 65, e 0..63   (16640 B)
// Reduction buffers: red[2][32*64] f64          (32 KB)
// Total static LDS ~ 57.9 KB (< 64 KB cap)

__global__ __launch_bounds__(512, 4)
void router_kernel(const float* __restrict__ hidden,
                   const float* __restrict__ gate_w,
                   const float* __restrict__ bias,
                   float* __restrict__ out)
{
    __shared__ float4 stH[16 * 33];
    __shared__ float4 stW[16 * 65];
    __shared__ double red[2][TB * EE];

    const int tid = threadIdx.x;
    const int s   = tid >> 7;        // h-split 0..3 (uniform per wave)
    const int r   = tid & 127;
    const int tg  = r >> 4;          // 0..7 -> tokens 4tg..4tg+3
    const int eg  = r & 15;          // experts eg + 16j
    const int tok0 = blockIdx.x * TB;

    // staging coordinates
    const int t_h  = tid >> 4;       // 0..31 (H token / W expert low)
    const int f4_h = tid & 15;       // 0..15 (h float4 slot)

    // acc[i][j] = logit(token 4tg+i, expert eg+16j), partial over split's h
    double acc[4][4];
    #pragma unroll
    for (int i = 0; i < 4; ++i)
        #pragma unroll
        for (int j = 0; j < 4; ++j) acc[i][j] = 0.0;

    // compute-side LDS bases (all inner offsets are compile-time immediates)
    const float4* pH = &stH[(s * 4) * 33 + 4 * tg];  // + u*33 + i
    const float4* pW = &stW[(s * 4) * 65 + eg];      // + u*65 + 16j

    // prologue: load chunk 0
    float4 hv, wv0, wv1;
    {
        const int c = 0;
        hv  = *reinterpret_cast<const float4*>(
            hidden + (size_t)(tok0 + t_h) * HH + c * HC + 4 * f4_h);
        wv0 = *reinterpret_cast<const float4*>(
            gate_w + (size_t)t_h * HH + c * HC + 4 * f4_h);
        wv1 = *reinterpret_cast<const float4*>(
            gate_w + (size_t)(t_h + 32) * HH + c * HC + 4 * f4_h);
    }

    for (int c = 0; c < NCH; ++c) {
        __syncthreads();   // previous chunk's compute done
        // stage (write-conflicts: 2-way max via padded strides)
        stH[f4_h * 33 + t_h]        = hv;
        stW[f4_h * 65 + t_h]        = wv0;
        stW[f4_h * 65 + t_h + 32]   = wv1;
        __syncthreads();   // staging visible (also drains ds_writes)

        // prefetch next chunk (completes under compute)
        if (c + 1 < NCH) {
            hv  = *reinterpret_cast<const float4*>(
                hidden + (size_t)(tok0 + t_h) * HH + (c + 1) * HC + 4 * f4_h);
            wv0 = *reinterpret_cast<const float4*>(
                gate_w + (size_t)t_h * HH + (c + 1) * HC + 4 * f4_h);
            wv1 = *reinterpret_cast<const float4*>(
                gate_w + (size_t)(t_h + 32) * HH + (c + 1) * HC + 4 * f4_h);
        }

        // compute: split s handles h-quads 4s..4s+3
        #pragma unroll
        for (int u = 0; u < 4; ++u) {
            float4 ha[4], wb[4];
            #pragma unroll
            for (int i = 0; i < 4; ++i) ha[i] = pH[u * 33 + i];
            #pragma unroll
            for (int j = 0; j < 4; ++j) wb[j] = pW[u * 65 + 16 * j];

            double hd[4][4], wd[4][4];
            #pragma unroll
            for (int i = 0; i < 4; ++i) {
                hd[i][0] = (double)ha[i].x; hd[i][1] = (double)ha[i].y;
                hd[i][2] = (double)ha[i].z; hd[i][3] = (double)ha[i].w;
            }
            #pragma unroll
            for (int j = 0; j < 4; ++j) {
                wd[j][0] = (double)wb[j].x; wd[j][1] = (double)wb[j].y;
                wd[j][2] = (double)wb[j].z; wd[j][3] = (double)wb[j].w;
            }
            #pragma unroll
            for (int i = 0; i < 4; ++i)
                #pragma unroll
                for (int j = 0; j < 4; ++j) {
                    acc[i][j] = fma(hd[i][0], wd[j][0], acc[i][j]);
                    acc[i][j] = fma(hd[i][1], wd[j][1], acc[i][j]);
                    acc[i][j] = fma(hd[i][2], wd[j][2], acc[i][j]);
                    acc[i][j] = fma(hd[i][3], wd[j][3], acc[i][j]);
                }
        }
    }

    // ---- reduce 4 split-partials: tree in LDS (5 barriers) ----
    __syncthreads();
    if (s == 2) {
        #pragma unroll
        for (int i = 0; i < 4; ++i)
            #pragma unroll
            for (int j = 0; j < 4; ++j)
                red[0][(4 * tg + i) * EE + eg + 16 * j] = acc[i][j];
    }
    if (s == 3) {
        #pragma unroll
        for (int i = 0; i < 4; ++i)
            #pragma unroll
            for (int j = 0; j < 4; ++j)
                red[1][(4 * tg + i) * EE + eg + 16 * j] = acc[i][j];
    }
    __syncthreads();
    if (s == 0) {
        #pragma unroll
        for (int i = 0; i < 4; ++i)
            #pragma unroll
            for (int j = 0; j < 4; ++j)
                acc[i][j] += red[0][(4 * tg + i) * EE + eg + 16 * j];
    }
    if (s == 1) {
        #pragma unroll
        for (int i = 0; i < 4; ++i)
            #pragma unroll
            for (int j = 0; j < 4; ++j)
                acc[i][j] += red[1][(4 * tg + i) * EE + eg + 16 * j];
    }
    __syncthreads();
    if (s == 1) {
        #pragma unroll
        for (int i = 0; i < 4; ++i)
            #pragma unroll
            for (int j = 0; j < 4; ++j)
                red[0][(4 * tg + i) * EE + eg + 16 * j] = acc[i][j];
    }
    __syncthreads();
    if (s == 0) {
        #pragma unroll
        for (int i = 0; i < 4; ++i)
            #pragma unroll
            for (int j = 0; j < 4; ++j) {
                acc[i][j] += red[0][(4 * tg + i) * EE + eg + 16 * j];
                red[1][(4 * tg + i) * EE + eg + 16 * j] = acc[i][j];
            }
    }
    __syncthreads();

    // ---- epilogue: 16 lanes per token (512 thr / 32 tok) ----
    const int t = tid >> 4;   // 0..31
    const int q = tid & 15;   // lane owns experts q + 16i, i = 0..3
    const int tok = tok0 + t;

    double lv[4];
    #pragma unroll
    for (int i = 0; i < 4; ++i) lv[i] = red[1][t * EE + q + 16 * i];

    // row max
    double mx = lv[0];
    #pragma unroll
    for (int i = 1; i < 4; ++i) mx = fmax(mx, lv[i]);
    #pragma unroll
    for (int sh = 1; sh < 16; sh <<= 1) mx = fmax(mx, __shfl_xor(mx, sh, 64));

    // exp + denom
    double ex[4], psum = 0.0;
    #pragma unroll
    for (int i = 0; i < 4; ++i) { ex[i] = exp(lv[i] - mx); psum += ex[i]; }
    #pragma unroll
    for (int sh = 1; sh < 16; sh <<= 1) psum += __shfl_xor(psum, sh, 64);
    const double inv = 1.0 / psum;

    double pr[4], selv[4];
    #pragma unroll
    for (int i = 0; i < 4; ++i) {
        pr[i]   = ex[i] * inv;
        selv[i] = pr[i] + (double)bias[q + 16 * i];
    }

    // top-8: lane-local argmax over 4, then 4-step shfl reduce (16 lanes)
    unsigned long long mk = 0ull;
    double myprob = 0.0;
    int myidx = 0;
    #pragma unroll
    for (int k = 0; k < KK; ++k) {
        double bs = selv[0], bp = pr[0];
        int bi = q;
        #pragma unroll
        for (int i = 1; i < 4; ++i) {
            if (selv[i] > bs) { bs = selv[i]; bp = pr[i]; bi = q + 16 * i; }
        }
        #pragma unroll
        for (int sh = 1; sh < 16; sh <<= 1) {
            double os = __shfl_xor(bs, sh, 64);
            double op = __shfl_xor(bp, sh, 64);
            int    oi = __shfl_xor(bi, sh, 64);
            if (os > bs || (os == bs && oi < bi)) { bs = os; bp = op; bi = oi; }
        }
        if (q == k) { myprob = bp; myidx = bi; }
        mk |= (1ull << bi);
        #pragma unroll
        for (int i = 0; i < 4; ++i)
            if (q + 16 * i == bi) selv[i] = -INFINITY;
    }

    // renormalize over the 8 winners
    double ps = (q < KK) ? myprob : 0.0;
    #pragma unroll
    for (int sh = 1; sh < 16; sh <<= 1) ps += __shfl_xor(ps, sh, 64);
    const double rinv = 1.0 / (ps + 1e-9);

    if (q < KK) {
        out[(size_t)tok * KK + q]           = (float)(myprob * rinv);
        out[IDX_OFF + (size_t)tok * KK + q] = (float)myidx;
    }

    // routing map: lane q writes experts 4q..4q+3 as one float4
    {
        float4 a;
        a.x = ((mk >> (4 * q + 0)) & 1ull) ? 1.0f : 0.0f;
        a.y = ((mk >> (4 * q + 1)) & 1ull) ? 1.0f : 0.0f;
        a.z = ((mk >> (4 * q + 2)) & 1ull) ? 1.0f : 0.0f;
        a.w = ((mk >> (4 * q + 3)) & 1ull) ? 1.0f : 0.0f;
        reinterpret_cast<float4*>(out + MAP_OFF + (size_t)tok * EE + 4 * q)[0] = a;
    }

    if (blockIdx.x == 0 && tid == 0) out[AUX_OFF] = 0.0f;
}

extern "C" void kernel_launch(void* const* d_in, const int* in_sizes, int n_in,
                              void* d_out, int out_size, void* d_ws, size_t ws_size,
                              hipStream_t stream) {
    const float* hidden = (const float*)d_in[0];  // [16384, 2048] f32
    const float* gate_w = (const float*)d_in[1];  // [64, 2048] f32
    const float* bias   = (const float*)d_in[2];  // [64] f32
    float* out = (float*)d_out;

    router_kernel<<<TT / TB, 512, 0, stream>>>(hidden, gate_w, bias, out);
}